// Round 8
// baseline (29.628 us; speedup 1.0000x reference)
//
#include <hip/hip_runtime.h>
#include <math.h>

#define NBINS 15
#define NBLK  512           // 2 blocks/CU on 256 CUs (1024-thread blocks)
#define WPB   16            // waves per block (1024 threads)
#define NWAVES (NBLK * WPB) // 8192 waves -> 4 rows/wave at B=32768

typedef float f4 __attribute__((ext_vector_type(4)));

// ---------------------------------------------------------------------------
// Main kernel: one WAVE per row (grid-stride), round-7 champion body, with
// REGISTER PREFETCH of the next row (fence-free this time: rounds 3/5 proved
// the 36x regression was the per-block device fence, NOT prefetch pressure).
// A compiler memory barrier pins the prefetch loads above the compute so the
// scheduler cannot sink them to their use (which would defeat the pipelining).
// VGPR budget: 16 cur + 16 next + ~20 temps < 64 cap at (1024,2).
// ---------------------------------------------------------------------------
__global__ __launch_bounds__(1024, 2) void fused_row_bin_kernel(
    const float* __restrict__ logits, const int* __restrict__ labels,
    float* __restrict__ partials, int B)
{
    const int lane = threadIdx.x & 63;
    const int wid  = threadIdx.x >> 6;

    // lane -> (stat t, bin j); boundaries match np.linspace: f32(i * (1/15 in double))
    const int   tsel = lane / 15;
    const int   jb   = lane - tsel * 15;
    const float lo   = (float)( jb      * (1.0 / 15.0));
    const float up   = (float)((jb + 1) * (1.0 / 15.0));

    float acc = 0.0f;
    const float NI = -INFINITY;

    // ---- prefetch first row ----
    int row = blockIdx.x * WPB + wid;
    f4 v0, v1, v2, v3;
    int lab = 0;
    if (row < B) {
        const f4* rp = reinterpret_cast<const f4*>(logits + (size_t)row * 1000);
        v0 = __builtin_nontemporal_load(rp + lane);
        v1 = __builtin_nontemporal_load(rp + lane + 64);
        v2 = __builtin_nontemporal_load(rp + lane + 128);
        if (lane < 58) v3 = __builtin_nontemporal_load(rp + lane + 192);
        else           v3 = (f4){NI, NI, NI, NI};
        lab = labels[row];
    }

    while (row < B) {
        // ---- issue next row's loads, then pin them above the compute ----
        const int nrow = row + NWAVES;
        f4 w0 = (f4){NI, NI, NI, NI}, w1 = w0, w2 = w0, w3 = w0;
        int nlab = 0;
        if (nrow < B) {
            const f4* rp = reinterpret_cast<const f4*>(logits + (size_t)nrow * 1000);
            w0 = __builtin_nontemporal_load(rp + lane);
            w1 = __builtin_nontemporal_load(rp + lane + 64);
            w2 = __builtin_nontemporal_load(rp + lane + 128);
            if (lane < 58) w3 = __builtin_nontemporal_load(rp + lane + 192);
            nlab = labels[nrow];
        }
        asm volatile("" ::: "memory");   // do not sink the loads below this

        // ---- lane-local max (value only), v_max3-friendly triples ----
        float t0 = fmaxf(fmaxf(v0.x, v0.y), v0.z);
        float t1 = fmaxf(fmaxf(v0.w, v1.x), v1.y);
        float t2 = fmaxf(fmaxf(v1.z, v1.w), v2.x);
        float t3 = fmaxf(fmaxf(v2.y, v2.z), v2.w);
        float t4 = fmaxf(fmaxf(v3.x, v3.y), v3.z);
        float m  = fmaxf(fmaxf(fmaxf(t0, t1), fmaxf(t2, t3)), fmaxf(t4, v3.w));

        // value-only butterfly: all lanes get row max M
        #pragma unroll
        for (int off = 1; off < 64; off <<= 1)
            m = fmaxf(m, __shfl_xor(m, off, 64));

        // ---- argmax via ballots: wave-uniform SGPR masks, SALU scan ----
        unsigned long long b00 = __ballot(v0.x == m), b01 = __ballot(v0.y == m);
        unsigned long long b02 = __ballot(v0.z == m), b03 = __ballot(v0.w == m);
        unsigned long long b10 = __ballot(v1.x == m), b11 = __ballot(v1.y == m);
        unsigned long long b12 = __ballot(v1.z == m), b13 = __ballot(v1.w == m);
        unsigned long long b20 = __ballot(v2.x == m), b21 = __ballot(v2.y == m);
        unsigned long long b22 = __ballot(v2.z == m), b23 = __ballot(v2.w == m);
        unsigned long long b30 = __ballot(v3.x == m), b31 = __ballot(v3.y == m);
        unsigned long long b32 = __ballot(v3.z == m), b33 = __ballot(v3.w == m);

        int best = 1 << 30;
        {
            // scan k = 3..0, overwrite: final best = first index
            unsigned long long u3 = b30 | b31 | b32 | b33;
            if (u3) {
                int l = __ffsll(u3) - 1;
                int c = ((b30 >> l) & 1) ? 0 : ((b31 >> l) & 1) ? 1 : ((b32 >> l) & 1) ? 2 : 3;
                best = 256 * 3 + 4 * l + c;
            }
            unsigned long long u2 = b20 | b21 | b22 | b23;
            if (u2) {
                int l = __ffsll(u2) - 1;
                int c = ((b20 >> l) & 1) ? 0 : ((b21 >> l) & 1) ? 1 : ((b22 >> l) & 1) ? 2 : 3;
                best = 256 * 2 + 4 * l + c;
            }
            unsigned long long u1 = b10 | b11 | b12 | b13;
            if (u1) {
                int l = __ffsll(u1) - 1;
                int c = ((b10 >> l) & 1) ? 0 : ((b11 >> l) & 1) ? 1 : ((b12 >> l) & 1) ? 2 : 3;
                best = 256 * 1 + 4 * l + c;
            }
            unsigned long long u0 = b00 | b01 | b02 | b03;
            if (u0) {
                int l = __ffsll(u0) - 1;
                int c = ((b00 >> l) & 1) ? 0 : ((b01 >> l) & 1) ? 1 : ((b02 >> l) & 1) ? 2 : 3;
                best = 4 * l + c;
            }
        }
        const float corr = (best == lab) ? 1.0f : 0.0f;

        // ---- sum of exp(l - M); -inf pads contribute exactly 0 ----
        float s = __expf(v0.x - m) + __expf(v0.y - m) + __expf(v0.z - m) + __expf(v0.w - m)
                + __expf(v1.x - m) + __expf(v1.y - m) + __expf(v1.z - m) + __expf(v1.w - m)
                + __expf(v2.x - m) + __expf(v2.y - m) + __expf(v2.z - m) + __expf(v2.w - m)
                + __expf(v3.x - m) + __expf(v3.y - m) + __expf(v3.z - m) + __expf(v3.w - m);
        #pragma unroll
        for (int off = 1; off < 64; off <<= 1) s += __shfl_xor(s, off, 64);

        const float conf = 1.0f / s;   // exp(M-M)=1 over Z

        // ---- fused soft-bin accumulation (lanes 0..44) ----
        if (lane < 45) {
            const float s1 = 1.0f / (1.0f + __expf(-20.0f * (conf - lo)));
            const float s2 = 1.0f / (1.0f + __expf(-20.0f * (up - conf)));
            const float ib = s1 * s2;
            const float wgt = (tsel == 0) ? 1.0f : ((tsel == 1) ? corr : conf);
            acc += ib * wgt;
        }

        row = nrow; lab = nlab;
        v0 = w0; v1 = w1; v2 = w2; v3 = w3;
    }

    // ---- fixed-order block combine -> transposed partials[j][block] ----
    __shared__ float part[WPB][48];
    if (lane < 45) part[wid][lane] = acc;
    __syncthreads();
    const int tid = threadIdx.x;
    if (tid < 45) {
        float s = part[0][tid];
        #pragma unroll
        for (int w = 1; w < WPB; ++w) s += part[w][tid];
        partials[(size_t)tid * NBLK + blockIdx.x] = s;
    }
}

// ---------------------------------------------------------------------------
// Finalize: one block, 16 waves. Wave w reduces rows j = w, w+16, w+32 of the
// transposed partials [45][NBLK]: 2 coalesced float4 loads/lane, fixed-order
// double accumulation + fixed-order double butterfly. Deterministic.
// (Bit-identical to round 7.)
// ---------------------------------------------------------------------------
__global__ __launch_bounds__(1024) void finalize_kernel(
    const float* __restrict__ partials, float* __restrict__ out, int B)
{
    const int tid  = threadIdx.x;
    const int lane = tid & 63;
    const int wid  = tid >> 6;           // 16 waves

    __shared__ double dsum[45];
    for (int j = wid; j < 45; j += 16) {
        const float4* fp = reinterpret_cast<const float4*>(partials + (size_t)j * NBLK);
        double s = 0.0;
        #pragma unroll
        for (int t = 0; t < NBLK / 256; ++t) {   // 512/4 float4 = 128 = 64 lanes x 2
            float4 v = fp[lane + 64 * t];
            s += (double)v.x; s += (double)v.y; s += (double)v.z; s += (double)v.w;
        }
        #pragma unroll
        for (int off = 1; off < 64; off <<= 1) s += __shfl_xor(s, off, 64);
        if (lane == 0) dsum[j] = s;
    }
    __syncthreads();

    __shared__ double term[NBINS];
    if (tid < NBINS) {
        const double mass = dsum[tid];
        const double accd = dsum[NBINS + tid]     / (mass + 1e-8);
        const double cfd  = dsum[2 * NBINS + tid] / (mass + 1e-8);
        const double d    = accd - cfd;
        term[tid] = d * d * mass;
    }
    __syncthreads();

    if (tid == 0) {
        double loss = 0.0;
        for (int i = 0; i < NBINS; ++i) loss += term[i];
        out[0] = (float)(loss / (double)B);
    }
}

// ---------------------------------------------------------------------------
// ws layout: partials[45 * NBLK] f32 = 90 KiB (fully overwritten every
// launch; no counters, no atomics, no fences -> poison-safe, fence-safe).
// ---------------------------------------------------------------------------
extern "C" void kernel_launch(void* const* d_in, const int* in_sizes, int n_in,
                              void* d_out, int out_size, void* d_ws, size_t ws_size,
                              hipStream_t stream)
{
    const float* logits = (const float*)d_in[0];
    const int*   labels = (const int*)d_in[1];
    const int B = in_sizes[1];   // 32768 rows; in_sizes[0]/B == 1000 classes

    float* partials = (float*)d_ws;

    fused_row_bin_kernel<<<NBLK, 1024, 0, stream>>>(logits, labels, partials, B);
    finalize_kernel<<<1, 1024, 0, stream>>>(partials, (float*)d_out, B);
}

// Round 9
// 27.673 us; speedup vs baseline: 1.0707x; 1.0707x over previous
//
#include <hip/hip_runtime.h>
#include <math.h>

#define NBINS 15
#define NBLK  512           // 2 blocks/CU on 256 CUs (1024-thread blocks)
#define WPB   16            // waves per block (1024 threads)
#define NWAVES (NBLK * WPB) // 8192 waves -> 4 rows/wave at B=32768

typedef float f4 __attribute__((ext_vector_type(4)));

// ---------------------------------------------------------------------------
// FINAL (round-7 champion, restored after the round-8 prefetch experiment
// regressed). One WAVE per row, grid-stride, no prefetch:
//   - prefetch is null/negative x3 (reg r1, LDS-DMA r4, pinned-reg r8):
//     per-CU load queues are already full (Little's law: row period ~15k cyc
//     vs ~600 cyc compute), so added queue depth buys nothing;
//   - NO device-scope fences / grid sync (rounds 3/5: per-block fence at
//     >=1024 blocks costs ~350us -- per-XCD L2 maintenance serializes);
//   - NT loads: input is poison-evicted every iteration, keep L2 clean;
//   - max: v_max3 tree + value-only butterfly; argmax: 16 ballots -> SGPR
//     masks + SALU first-index scan; conf = 1/sum exp(l - M);
//   - lanes 0..44 accumulate soft-bin stats (t=lane/15: mass/acc/conf-mass);
//   - fixed-order combine everywhere; double-precision finalize -> absmax 0.
// Achieved: ~5.1 TB/s cold-HBM read in main (FETCH = ideal 131 MB),
// finalize ~0.8us, gap ~1.5us => ~28us total. Roofline for this pattern.
// ---------------------------------------------------------------------------
__global__ __launch_bounds__(1024, 2) void fused_row_bin_kernel(
    const float* __restrict__ logits, const int* __restrict__ labels,
    float* __restrict__ partials, int B)
{
    const int lane = threadIdx.x & 63;
    const int wid  = threadIdx.x >> 6;

    // lane -> (stat t, bin j); boundaries match np.linspace: f32(i * (1/15 in double))
    const int   tsel = lane / 15;
    const int   jb   = lane - tsel * 15;
    const float lo   = (float)( jb      * (1.0 / 15.0));
    const float up   = (float)((jb + 1) * (1.0 / 15.0));

    float acc = 0.0f;
    const float NI = -INFINITY;

    for (int row = blockIdx.x * WPB + wid; row < B; row += NWAVES) {
        const f4* rp = reinterpret_cast<const f4*>(logits + (size_t)row * 1000);
        f4 v0 = __builtin_nontemporal_load(rp + lane);
        f4 v1 = __builtin_nontemporal_load(rp + lane + 64);
        f4 v2 = __builtin_nontemporal_load(rp + lane + 128);
        f4 v3;
        if (lane < 58) v3 = __builtin_nontemporal_load(rp + lane + 192);
        else           v3 = (f4){NI, NI, NI, NI};
        const int lab = labels[row];

        // ---- lane-local max (value only), v_max3-friendly triples ----
        float t0 = fmaxf(fmaxf(v0.x, v0.y), v0.z);
        float t1 = fmaxf(fmaxf(v0.w, v1.x), v1.y);
        float t2 = fmaxf(fmaxf(v1.z, v1.w), v2.x);
        float t3 = fmaxf(fmaxf(v2.y, v2.z), v2.w);
        float t4 = fmaxf(fmaxf(v3.x, v3.y), v3.z);
        float m  = fmaxf(fmaxf(fmaxf(t0, t1), fmaxf(t2, t3)), fmaxf(t4, v3.w));

        // value-only butterfly: all lanes get row max M
        #pragma unroll
        for (int off = 1; off < 64; off <<= 1)
            m = fmaxf(m, __shfl_xor(m, off, 64));

        // ---- argmax via ballots: wave-uniform SGPR masks, SALU scan ----
        unsigned long long b00 = __ballot(v0.x == m), b01 = __ballot(v0.y == m);
        unsigned long long b02 = __ballot(v0.z == m), b03 = __ballot(v0.w == m);
        unsigned long long b10 = __ballot(v1.x == m), b11 = __ballot(v1.y == m);
        unsigned long long b12 = __ballot(v1.z == m), b13 = __ballot(v1.w == m);
        unsigned long long b20 = __ballot(v2.x == m), b21 = __ballot(v2.y == m);
        unsigned long long b22 = __ballot(v2.z == m), b23 = __ballot(v2.w == m);
        unsigned long long b30 = __ballot(v3.x == m), b31 = __ballot(v3.y == m);
        unsigned long long b32 = __ballot(v3.z == m), b33 = __ballot(v3.w == m);

        int best = 1 << 30;
        {
            // scan k = 3..0, overwrite: final best = first index
            unsigned long long u3 = b30 | b31 | b32 | b33;
            if (u3) {
                int l = __ffsll(u3) - 1;
                int c = ((b30 >> l) & 1) ? 0 : ((b31 >> l) & 1) ? 1 : ((b32 >> l) & 1) ? 2 : 3;
                best = 256 * 3 + 4 * l + c;
            }
            unsigned long long u2 = b20 | b21 | b22 | b23;
            if (u2) {
                int l = __ffsll(u2) - 1;
                int c = ((b20 >> l) & 1) ? 0 : ((b21 >> l) & 1) ? 1 : ((b22 >> l) & 1) ? 2 : 3;
                best = 256 * 2 + 4 * l + c;
            }
            unsigned long long u1 = b10 | b11 | b12 | b13;
            if (u1) {
                int l = __ffsll(u1) - 1;
                int c = ((b10 >> l) & 1) ? 0 : ((b11 >> l) & 1) ? 1 : ((b12 >> l) & 1) ? 2 : 3;
                best = 256 * 1 + 4 * l + c;
            }
            unsigned long long u0 = b00 | b01 | b02 | b03;
            if (u0) {
                int l = __ffsll(u0) - 1;
                int c = ((b00 >> l) & 1) ? 0 : ((b01 >> l) & 1) ? 1 : ((b02 >> l) & 1) ? 2 : 3;
                best = 4 * l + c;
            }
        }
        const float corr = (best == lab) ? 1.0f : 0.0f;

        // ---- sum of exp(l - M); -inf pads contribute exactly 0 ----
        float s = __expf(v0.x - m) + __expf(v0.y - m) + __expf(v0.z - m) + __expf(v0.w - m)
                + __expf(v1.x - m) + __expf(v1.y - m) + __expf(v1.z - m) + __expf(v1.w - m)
                + __expf(v2.x - m) + __expf(v2.y - m) + __expf(v2.z - m) + __expf(v2.w - m)
                + __expf(v3.x - m) + __expf(v3.y - m) + __expf(v3.z - m) + __expf(v3.w - m);
        #pragma unroll
        for (int off = 1; off < 64; off <<= 1) s += __shfl_xor(s, off, 64);

        const float conf = 1.0f / s;   // exp(M-M)=1 over Z

        // ---- fused soft-bin accumulation (lanes 0..44) ----
        if (lane < 45) {
            const float s1 = 1.0f / (1.0f + __expf(-20.0f * (conf - lo)));
            const float s2 = 1.0f / (1.0f + __expf(-20.0f * (up - conf)));
            const float ib = s1 * s2;
            const float wgt = (tsel == 0) ? 1.0f : ((tsel == 1) ? corr : conf);
            acc += ib * wgt;
        }
    }

    // ---- fixed-order block combine -> transposed partials[j][block] ----
    __shared__ float part[WPB][48];
    if (lane < 45) part[wid][lane] = acc;
    __syncthreads();
    const int tid = threadIdx.x;
    if (tid < 45) {
        float s = part[0][tid];
        #pragma unroll
        for (int w = 1; w < WPB; ++w) s += part[w][tid];
        partials[(size_t)tid * NBLK + blockIdx.x] = s;
    }
}

// ---------------------------------------------------------------------------
// Finalize: one block, 16 waves. Wave w reduces rows j = w, w+16, w+32 of the
// transposed partials [45][NBLK]: 2 coalesced float4 loads/lane, fixed-order
// double accumulation + fixed-order double butterfly. Deterministic.
// ---------------------------------------------------------------------------
__global__ __launch_bounds__(1024) void finalize_kernel(
    const float* __restrict__ partials, float* __restrict__ out, int B)
{
    const int tid  = threadIdx.x;
    const int lane = tid & 63;
    const int wid  = tid >> 6;           // 16 waves

    __shared__ double dsum[45];
    for (int j = wid; j < 45; j += 16) {
        const float4* fp = reinterpret_cast<const float4*>(partials + (size_t)j * NBLK);
        double s = 0.0;
        #pragma unroll
        for (int t = 0; t < NBLK / 256; ++t) {   // 512/4 float4 = 128 = 64 lanes x 2
            float4 v = fp[lane + 64 * t];
            s += (double)v.x; s += (double)v.y; s += (double)v.z; s += (double)v.w;
        }
        #pragma unroll
        for (int off = 1; off < 64; off <<= 1) s += __shfl_xor(s, off, 64);
        if (lane == 0) dsum[j] = s;
    }
    __syncthreads();

    __shared__ double term[NBINS];
    if (tid < NBINS) {
        const double mass = dsum[tid];
        const double accd = dsum[NBINS + tid]     / (mass + 1e-8);
        const double cfd  = dsum[2 * NBINS + tid] / (mass + 1e-8);
        const double d    = accd - cfd;
        term[tid] = d * d * mass;
    }
    __syncthreads();

    if (tid == 0) {
        double loss = 0.0;
        for (int i = 0; i < NBINS; ++i) loss += term[i];
        out[0] = (float)(loss / (double)B);
    }
}

// ---------------------------------------------------------------------------
// ws layout: partials[45 * NBLK] f32 = 90 KiB (fully overwritten every
// launch; no counters, no atomics, no fences -> poison-safe, fence-safe).
// ---------------------------------------------------------------------------
extern "C" void kernel_launch(void* const* d_in, const int* in_sizes, int n_in,
                              void* d_out, int out_size, void* d_ws, size_t ws_size,
                              hipStream_t stream)
{
    const float* logits = (const float*)d_in[0];
    const int*   labels = (const int*)d_in[1];
    const int B = in_sizes[1];   // 32768 rows; in_sizes[0]/B == 1000 classes

    float* partials = (float*)d_ws;

    fused_row_bin_kernel<<<NBLK, 1024, 0, stream>>>(logits, labels, partials, B);
    finalize_kernel<<<1, 1024, 0, stream>>>(partials, (float*)d_out, B);
}